// Round 1
// baseline (33879.910 us; speedup 1.0000x reference)
//
#include <hip/hip_runtime.h>
#include <hip/hip_cooperative_groups.h>

namespace cg = cooperative_groups;

#define BATCH 256
#define SEQL  512
#define DIN   256
#define DH    512
#define NG    2048   // 4*DH, gate-interleaved: col n = 4*unit + gate (0=g,1=i,2=f,3=o)
#define KTOT  768    // DIN + DH
#define BK    32
#define TM    64     // rows (batch) per block
#define TN    32     // cols (gates) per block  -> 8 complete units
#define NCLS  1024

// ---------------------------------------------------------------------------
// Pack weights into k-major [KTOT][NG] with gate-interleaved columns, pack
// biases, and zero the initial h buffer.
// ---------------------------------------------------------------------------
__global__ void pack_kernel(const float* __restrict__ Wgx, const float* __restrict__ Wgh,
                            const float* __restrict__ Wix, const float* __restrict__ Wih,
                            const float* __restrict__ Wfx, const float* __restrict__ Wfh,
                            const float* __restrict__ Wox, const float* __restrict__ Woh,
                            const float* __restrict__ bg,  const float* __restrict__ bi,
                            const float* __restrict__ bf,  const float* __restrict__ bo,
                            float* __restrict__ Wp, float* __restrict__ bp,
                            float* __restrict__ h0)
{
    int idx = blockIdx.x * blockDim.x + threadIdx.x;
    const int total = KTOT * NG;
    if (idx < total) {
        int k = idx / NG;
        int n = idx - k * NG;
        int unit = n >> 2;
        int gate = n & 3;
        float v;
        if (k < DIN) {
            const float* src = (gate == 0) ? Wgx : (gate == 1) ? Wix : (gate == 2) ? Wfx : Wox;
            v = src[k * DH + unit];
        } else {
            const float* src = (gate == 0) ? Wgh : (gate == 1) ? Wih : (gate == 2) ? Wfh : Woh;
            v = src[(k - DIN) * DH + unit];
        }
        Wp[idx] = v;
    }
    if (idx < NG) {
        int unit = idx >> 2;
        int gate = idx & 3;
        const float* bsrc = (gate == 0) ? bg : (gate == 1) ? bi : (gate == 2) ? bf : bo;
        bp[idx] = bsrc[unit];
    }
    if (idx < BATCH * DH) h0[idx] = 0.f;
}

// ---------------------------------------------------------------------------
// Persistent cooperative LSTM kernel: 512 sequential steps, one grid.sync each.
// 256 blocks x 256 threads. Block tile 64 rows x 32 gate-cols. Thread micro-
// tile 2 rows x 4 cols (= one complete unit's g,i,f,o for 2 batch rows), so
// the c/h update is thread-local. c lives in registers for the whole kernel.
// ---------------------------------------------------------------------------
__global__ __launch_bounds__(256, 1) void lstm_main(
    const float* __restrict__ x, const float* __restrict__ Wp,
    const float* __restrict__ bp, float* __restrict__ h0, float* __restrict__ h1)
{
    __shared__ __align__(16) float As[BK][TM + 2];  // stride 66 floats: 8B-aligned float2, 2-way-max bank conflicts
    __shared__ __align__(16) float Bs[BK][TN + 4];  // stride 36 floats: 16B-aligned float4, conflict-free

    const int tid = threadIdx.x;
    const int bid = blockIdx.x;
    const int r0 = (bid & 3) * TM;        // 4 row tiles
    const int n0 = (bid >> 2) * TN;       // 64 col tiles
    const int tx = tid & 7;               // unit within tile (owns cols 4tx..4tx+3)
    const int ty = tid >> 3;              // row pair (rows 2ty, 2ty+1)
    const int unit = (n0 >> 2) + tx;
    const int row0 = r0 + 2 * ty;

    // loader lane mapping
    const int lk  = tid & 31;             // k within chunk (A loads)
    const int lr  = tid >> 5;             // row base (A loads), rows lr + 8i
    const int ln  = tid & 31;             // col (B loads)
    const int lbk = tid >> 5;             // k base (B loads), k = lbk + 8i

    float c0 = 0.f, c1 = 0.f;
    const float b_g = bp[n0 + 4 * tx + 0];
    const float b_i = bp[n0 + 4 * tx + 1];
    const float b_f = bp[n0 + 4 * tx + 2];
    const float b_o = bp[n0 + 4 * tx + 3];

    cg::grid_group grid = cg::this_grid();
    float* hb[2] = {h0, h1};

    for (int t = 0; t < SEQL; ++t) {
        const float* __restrict__ hin = hb[t & 1];
        float* __restrict__ hout = hb[(t + 1) & 1];

        float aPre[8], bPre[4];
        // prefetch chunk kk=0 (pure x-part: safe right after sync, doesn't touch h)
        {
            const float* xbase = x + (size_t)t * DIN;
            #pragma unroll
            for (int i = 0; i < 8; ++i) {
                int r = r0 + lr + i * 8;
                aPre[i] = xbase[(size_t)r * (SEQL * DIN) + lk];
            }
            #pragma unroll
            for (int i = 0; i < 4; ++i) {
                int k = lbk + i * 8;
                bPre[i] = Wp[(size_t)k * NG + n0 + ln];
            }
        }

        float acc[2][4];
        #pragma unroll
        for (int i = 0; i < 2; ++i)
            #pragma unroll
            for (int j = 0; j < 4; ++j) acc[i][j] = 0.f;

        for (int kk = 0; kk < KTOT; kk += BK) {
            __syncthreads();
            #pragma unroll
            for (int i = 0; i < 8; ++i) As[lk][lr + i * 8] = aPre[i];
            #pragma unroll
            for (int i = 0; i < 4; ++i) Bs[lbk + i * 8][ln] = bPre[i];
            __syncthreads();

            const int kn = kk + BK;
            if (kn < KTOT) {
                // prefetch next chunk into registers; loads fly during compute below
                if (kn < DIN) {
                    const float* xbase = x + (size_t)t * DIN + kn;
                    #pragma unroll
                    for (int i = 0; i < 8; ++i) {
                        int r = r0 + lr + i * 8;
                        aPre[i] = xbase[(size_t)r * (SEQL * DIN) + lk];
                    }
                } else {
                    const float* hbase = hin + (kn - DIN);
                    #pragma unroll
                    for (int i = 0; i < 8; ++i) {
                        int r = r0 + lr + i * 8;
                        aPre[i] = hbase[(size_t)r * DH + lk];
                    }
                }
                #pragma unroll
                for (int i = 0; i < 4; ++i) {
                    int k = lbk + i * 8;
                    bPre[i] = Wp[(size_t)(kn + k) * NG + n0 + ln];
                }
            }

            #pragma unroll
            for (int k = 0; k < BK; ++k) {
                const float2 a = *(const float2*)&As[k][2 * ty];
                const float4 w = *(const float4*)&Bs[k][4 * tx];
                acc[0][0] += a.x * w.x; acc[0][1] += a.x * w.y;
                acc[0][2] += a.x * w.z; acc[0][3] += a.x * w.w;
                acc[1][0] += a.y * w.x; acc[1][1] += a.y * w.y;
                acc[1][2] += a.y * w.z; acc[1][3] += a.y * w.w;
            }
        }

        // activations + state update (thread-local c), write h to other buffer
        #pragma unroll
        for (int i = 0; i < 2; ++i) {
            float zg = acc[i][0] + b_g;
            float zi = acc[i][1] + b_i;
            float zf = acc[i][2] + b_f;
            float zo = acc[i][3] + b_o;
            float gv = 1.0f / (1.0f + expf(-zg));   // sigmoid on 'g' (reference quirk)
            float iv = tanhf(zi);
            float fv = tanhf(zf);
            float ov = tanhf(zo);
            float cr = (i == 0) ? c0 : c1;
            cr = gv * iv + cr * fv;
            if (i == 0) c0 = cr; else c1 = cr;
            float hv = tanhf(cr) * ov;
            hout[(size_t)(row0 + i) * DH + unit] = hv;
        }

        grid.sync();
    }
}

// ---------------------------------------------------------------------------
// Final projection + softmax, fused. One block per batch row; 256 threads,
// 4 columns each. h[r][k] is a uniform broadcast load per k.
// ---------------------------------------------------------------------------
__global__ __launch_bounds__(256) void proj_softmax(
    const float* __restrict__ h, const float* __restrict__ Wph,
    const float* __restrict__ bP, float* __restrict__ out)
{
    __shared__ float red[256];
    const int r = blockIdx.x;
    const int tid = threadIdx.x;
    float a0 = 0.f, a1 = 0.f, a2 = 0.f, a3 = 0.f;
    const float* hr = h + (size_t)r * DH;
    for (int k = 0; k < DH; ++k) {
        float hv = hr[k];
        const float* w = Wph + (size_t)k * NCLS;
        a0 += hv * w[tid];
        a1 += hv * w[tid + 256];
        a2 += hv * w[tid + 512];
        a3 += hv * w[tid + 768];
    }
    a0 += bP[tid]; a1 += bP[tid + 256]; a2 += bP[tid + 512]; a3 += bP[tid + 768];

    // row max
    float m = fmaxf(fmaxf(a0, a1), fmaxf(a2, a3));
    red[tid] = m; __syncthreads();
    for (int s = 128; s > 0; s >>= 1) {
        if (tid < s) red[tid] = fmaxf(red[tid], red[tid + s]);
        __syncthreads();
    }
    m = red[0];
    __syncthreads();

    float e0 = expf(a0 - m), e1 = expf(a1 - m), e2 = expf(a2 - m), e3 = expf(a3 - m);
    red[tid] = e0 + e1 + e2 + e3; __syncthreads();
    for (int s = 128; s > 0; s >>= 1) {
        if (tid < s) red[tid] += red[tid + s];
        __syncthreads();
    }
    const float inv = 1.0f / red[0];

    float* o = out + (size_t)r * NCLS;
    o[tid]       = e0 * inv;
    o[tid + 256] = e1 * inv;
    o[tid + 512] = e2 * inv;
    o[tid + 768] = e3 * inv;
}

// ---------------------------------------------------------------------------
extern "C" void kernel_launch(void* const* d_in, const int* in_sizes, int n_in,
                              void* d_out, int out_size, void* d_ws, size_t ws_size,
                              hipStream_t stream)
{
    const float* x   = (const float*)d_in[0];
    const float* Wgx = (const float*)d_in[1];
    const float* Wgh = (const float*)d_in[2];
    const float* bg  = (const float*)d_in[3];
    const float* Wix = (const float*)d_in[4];
    const float* Wih = (const float*)d_in[5];
    const float* bi  = (const float*)d_in[6];
    const float* Wfx = (const float*)d_in[7];
    const float* Wfh = (const float*)d_in[8];
    const float* bf  = (const float*)d_in[9];
    const float* Wox = (const float*)d_in[10];
    const float* Woh = (const float*)d_in[11];
    const float* bo  = (const float*)d_in[12];
    const float* Wph = (const float*)d_in[13];
    const float* bP  = (const float*)d_in[14];

    float* ws = (float*)d_ws;
    float* Wp = ws;                              // [768][2048]
    float* bp = Wp + (size_t)KTOT * NG;          // [2048]
    float* h0 = bp + NG;                         // [256][512]
    float* h1 = h0 + (size_t)BATCH * DH;         // [256][512]

    pack_kernel<<<(KTOT * NG + 255) / 256, 256, 0, stream>>>(
        Wgx, Wgh, Wix, Wih, Wfx, Wfh, Wox, Woh, bg, bi, bf, bo, Wp, bp, h0);

    void* args[] = {(void*)&x, (void*)&Wp, (void*)&bp, (void*)&h0, (void*)&h1};
    hipLaunchCooperativeKernel((void*)lstm_main, dim3(256), dim3(256), args, 0, stream);

    // final h is in h0 (512 steps -> buffer parity 0)
    proj_softmax<<<BATCH, 256, 0, stream>>>(h0, Wph, bP, (float*)d_out);
}